// Round 12
// baseline (84.187 us; speedup 1.0000x reference)
//
#include <hip/hip_runtime.h>
#include <hip/hip_bf16.h>
#include <stdint.h>

// BS=16, T=16, N=512, C=128, E=128, OUT=256; P=8192, BT=256
// square[b,t,n,c] = feats[b, n*T+t, c]
// x1[e][bt][c] = sum_n square[n][c]*eig[e][n]          (bf16, ws)
// x3[bt][o][e] = sum_c x1[e][bt][c]*paramT[e][o][c]    (bf16, ws)
// out[bt][n][o] = relu(sum_e x3[bt][o][e]*eigT[n][e])  (f32, d_out)

typedef short bf16x8 __attribute__((ext_vector_type(8)));
typedef float f32x4 __attribute__((ext_vector_type(4)));

__device__ __forceinline__ ushort f2bf(float x) {
  __hip_bfloat16 h = __float2bfloat16(x);   // RNE, lowers to HW cvt on gfx950
  return *(ushort*)&h;
}

// ---------------- prep (merged): paramT + eig_bf + eigT ----------------
__global__ __launch_bounds__(256) void k_prep(const float* __restrict__ param,
                                              const float* __restrict__ eig,
                                              ushort* __restrict__ paramT,
                                              ushort* __restrict__ eig_bf,
                                              ushort* __restrict__ eigT) {
  int bid = blockIdx.x, tid = threadIdx.x;
  if (bid < 256) {
    int o = bid;
    int c = tid & 127, h = tid >> 7;
#pragma unroll 4
    for (int ee = 0; ee < 64; ++ee) {
      int e = h * 64 + ee;
      paramT[(size_t)e * 32768 + o * 128 + c] = f2bf(param[(size_t)o * 16384 + c * 128 + e]);
    }
  } else if (bid < 384) {
    int e = bid - 256;
    eig_bf[e * 512 + tid] = f2bf(eig[e * 512 + tid]);
    eig_bf[e * 512 + 256 + tid] = f2bf(eig[e * 512 + 256 + tid]);
  } else {
    int idx = bid - 384;                 // 0..127, 4 n-rows each
    int n = idx * 4 + (tid >> 6);
    int e0 = (tid & 63) * 2;
    ushort2 pk;
    pk.x = f2bf(eig[(size_t)e0 * 512 + n]);
    pk.y = f2bf(eig[(size_t)(e0 + 1) * 512 + n]);
    *(ushort2*)(eigT + n * 128 + e0) = pk;
  }
}

// ---------------- stage 1: x1[e][bt][c] ----------------
// grid 512 x 512 thr: (bt, c-half) -> 2 independent blocks/CU, 16 waves/CU.
// Role-split staging: threads 0-255 transpose feats (4x4 packed b64 writes),
// threads 256-511 copy eig rows. Cross-block overlap hides HBM latency.
__global__ __launch_bounds__(512) void k_stage1(const float* __restrict__ feats,
                                                const ushort* __restrict__ eig_bf,
                                                ushort* __restrict__ x1) {
  int bid = blockIdx.x;
  int bt = bid >> 1, ch = bid & 1;
  int b = bt >> 4, tt = bt & 15;
  __shared__ ushort As[64 * 72];   // [c-local 64][n-chunk 64, pad 72]
  __shared__ ushort Bs[128 * 72];  // [e 128][n-chunk 64, pad 72]
  int tid = threadIdx.x, l = tid & 63, w = tid >> 6;   // w 0..7
  int wr = (w & 1) * 32;   // c-local offset (2-way)
  int wc = (w >> 1) * 32;  // e offset (4-way)
  int lr = l & 15, lg = l >> 4;
  f32x4 acc[2][2] = {};
  const float* fbase = feats + (size_t)b * (8192 * 128) + (size_t)tt * 128 + ch * 64;

  // staging roles
  int nq = tid & 15;             // A-role: n-quad
  int cq = (tid >> 4) & 15;      // A-role: c-quad (c0 = cq*4, 0..60)
  int lb = tid - 256;            // B-role local id
  int partB = lb & 7, erB = lb >> 3;

  for (int nc = 0; nc < 8; ++nc) {
    int n0 = nc * 64;
    if (tid < 256) {
      // ---- A: transpose 4x4 feats into As[c][n], packed b64 writes ----
      int c0 = cq * 4;
      const float* p = fbase + (size_t)(n0 + nq * 4) * 2048 + c0;
      float4 v0 = *(const float4*)(p);
      float4 v1 = *(const float4*)(p + 2048);
      float4 v2 = *(const float4*)(p + 4096);
      float4 v3 = *(const float4*)(p + 6144);
      const float* a0 = (const float*)&v0;
      const float* a1 = (const float*)&v1;
      const float* a2 = (const float*)&v2;
      const float* a3 = (const float*)&v3;
#pragma unroll
      for (int k = 0; k < 4; ++k) {
        ushort4 q;
        q.x = f2bf(a0[k]);
        q.y = f2bf(a1[k]);
        q.z = f2bf(a2[k]);
        q.w = f2bf(a3[k]);
        *(ushort4*)&As[(c0 + k) * 72 + nq * 4] = q;   // byte 144c+8nq: b64-aligned
      }
    } else {
      // ---- B: eig rows linear copy (128 rows x 128B, 64B/thread) ----
#pragma unroll
      for (int p = 0; p < 4; ++p) {
        int e = erB + p * 32;
        uint4 v = *(const uint4*)(eig_bf + (size_t)e * 512 + n0 + partB * 8);
        *(uint4*)&Bs[e * 72 + partB * 8] = v;
      }
    }
    __syncthreads();
#pragma unroll
    for (int kk = 0; kk < 64; kk += 32) {
      bf16x8 af[2], bg[2];
#pragma unroll
      for (int fm = 0; fm < 2; ++fm)
        af[fm] = *(const bf16x8*)&As[(wr + fm * 16 + lr) * 72 + kk + lg * 8];
#pragma unroll
      for (int fn = 0; fn < 2; ++fn)
        bg[fn] = *(const bf16x8*)&Bs[(wc + fn * 16 + lr) * 72 + kk + lg * 8];
#pragma unroll
      for (int fm = 0; fm < 2; ++fm)
#pragma unroll
        for (int fn = 0; fn < 2; ++fn)
          acc[fm][fn] = __builtin_amdgcn_mfma_f32_16x16x32_bf16(af[fm], bg[fn], acc[fm][fn], 0, 0, 0);
    }
    __syncthreads();
  }
  // epilogue: x1[e][bt][c] 8B packed
#pragma unroll
  for (int fm = 0; fm < 2; ++fm) {
    int c = ch * 64 + wr + fm * 16 + lg * 4;
#pragma unroll
    for (int fn = 0; fn < 2; ++fn) {
      int e = wc + fn * 16 + lr;
      ushort4 pk;
      pk.x = f2bf(acc[fm][fn][0]);
      pk.y = f2bf(acc[fm][fn][1]);
      pk.z = f2bf(acc[fm][fn][2]);
      pk.w = f2bf(acc[fm][fn][3]);
      *(ushort4*)(x1 + (size_t)e * 32768 + bt * 128 + c) = pk;
    }
  }
}

// ---------------- stage 2: x3[bt][o][e] ----------------
// grid 1024: (btb 0..3) x (ob 0..3) x (ec 0..63), 2 e per block -> 4 blocks/CU.
// Same per-e structure/traffic; more independent blocks interleave the rounds.
__global__ __launch_bounds__(256) void k_stage2(const ushort* __restrict__ x1,
                                                const ushort* __restrict__ paramT,
                                                ushort* __restrict__ x3) {
  int bx = blockIdx.x;
  int btb = bx & 3, ob = (bx >> 2) & 3, ec = bx >> 4;   // ec 0..63
  int bt0 = btb * 64, o0 = ob * 64, e0 = ec * 2;
  __shared__ ushort As[64 * 136];  // [bt][c pad 136]
  __shared__ ushort Bs[64 * 136];  // [o][c pad 136]
  int tid = threadIdx.x, l = tid & 63, w = tid >> 6;
  int wbt = (w & 1) * 32, wo = (w >> 1) * 32;
  int lr = l & 15, lg = l >> 4;

  float res[2][2][4][2];
#pragma unroll
  for (int ei = 0; ei < 2; ++ei) {
    int e = e0 + ei;
    {
      int part = tid & 15, row = tid >> 4;
#pragma unroll
      for (int p = 0; p < 4; ++p) {
        int r_ = row + p * 16;
        uint4 va = *(const uint4*)(x1 + (size_t)e * 32768 + (bt0 + r_) * 128 + part * 8);
        *(uint4*)&As[r_ * 136 + part * 8] = va;
        uint4 vb = *(const uint4*)(paramT + (size_t)e * 32768 + (o0 + r_) * 128 + part * 8);
        *(uint4*)&Bs[r_ * 136 + part * 8] = vb;
      }
    }
    __syncthreads();
    f32x4 acc[2][2] = {};
#pragma unroll
    for (int kk = 0; kk < 128; kk += 32) {
      bf16x8 af[2], bg[2];
#pragma unroll
      for (int fm = 0; fm < 2; ++fm)
        af[fm] = *(const bf16x8*)&As[(wbt + fm * 16 + lr) * 136 + kk + lg * 8];
#pragma unroll
      for (int fn = 0; fn < 2; ++fn)
        bg[fn] = *(const bf16x8*)&Bs[(wo + fn * 16 + lr) * 136 + kk + lg * 8];
#pragma unroll
      for (int fm = 0; fm < 2; ++fm)
#pragma unroll
        for (int fn = 0; fn < 2; ++fn)
          acc[fm][fn] = __builtin_amdgcn_mfma_f32_16x16x32_bf16(af[fm], bg[fn], acc[fm][fn], 0, 0, 0);
    }
    __syncthreads();
#pragma unroll
    for (int fm = 0; fm < 2; ++fm)
#pragma unroll
      for (int fn = 0; fn < 2; ++fn)
#pragma unroll
        for (int r = 0; r < 4; ++r) res[fm][fn][r][ei] = acc[fm][fn][r];
  }
#pragma unroll
  for (int fm = 0; fm < 2; ++fm) {
    int btl = bt0 + wbt + fm * 16 + lg * 4;
#pragma unroll
    for (int fn = 0; fn < 2; ++fn) {
      int o = o0 + wo + fn * 16 + lr;
#pragma unroll
      for (int r = 0; r < 4; ++r) {
        ushort2 pk;
        pk.x = f2bf(res[fm][fn][r][0]);
        pk.y = f2bf(res[fm][fn][r][1]);
        *(ushort2*)(x3 + (size_t)(btl + r) * 32768 + o * 128 + e0) = pk;
      }
    }
  }
}

// ---------------- stage 3: out = relu(x3 @ eigT^T) ----------------
// grid 512 (bt, o-half) x 512 thr: 8 waves (2o x 4n), 16 waves/CU.
// As (x3 o-slice, full e=128) staged once; 4 n-chunks of 128 via Bs.
__global__ __launch_bounds__(512) void k_stage3(const ushort* __restrict__ x3,
                                                const ushort* __restrict__ eigT,
                                                float* __restrict__ out) {
  int bx = blockIdx.x;
  int bt = bx >> 1, ob = bx & 1;
  int o0 = ob * 128;
  __shared__ ushort As[128 * 136];  // [o 128][e 128 pad 136]
  __shared__ ushort Bs[128 * 136];  // [n 128][e 128 pad 136]
  int tid = threadIdx.x, l = tid & 63, w = tid >> 6;   // w 0..7
  int lr = l & 15, lg = l >> 4;
  int wo = (w & 1) * 64;    // o offset (2-way)
  int wn = (w >> 1) * 32;   // n offset (4-way)
  const ushort* pa = x3 + (size_t)bt * 32768 + (size_t)o0 * 128;
  int part = tid & 15, row = tid >> 4;   // 32 rows/pass with 512 thr

  // stage As once: 128 rows x 256B (4 passes)
#pragma unroll
  for (int p = 0; p < 4; ++p) {
    int r_ = row + p * 32;
    uint4 va = *(const uint4*)(pa + (size_t)r_ * 128 + part * 8);
    *(uint4*)&As[r_ * 136 + part * 8] = va;
  }

  for (int nb = 0; nb < 4; ++nb) {
    int n0 = nb * 128;
    __syncthreads();   // As ready (iter0) / prev Bs readers done
#pragma unroll
    for (int p = 0; p < 4; ++p) {
      int r_ = row + p * 32;
      uint4 vb = *(const uint4*)(eigT + (size_t)(n0 + r_) * 128 + part * 8);
      *(uint4*)&Bs[r_ * 136 + part * 8] = vb;
    }
    __syncthreads();
    f32x4 acc[4][2] = {};
#pragma unroll
    for (int kk = 0; kk < 128; kk += 32) {
      bf16x8 af[4], bg[2];
#pragma unroll
      for (int fm = 0; fm < 4; ++fm)
        af[fm] = *(const bf16x8*)&As[(wo + fm * 16 + lr) * 136 + kk + lg * 8];
#pragma unroll
      for (int fn = 0; fn < 2; ++fn)
        bg[fn] = *(const bf16x8*)&Bs[(wn + fn * 16 + lr) * 136 + kk + lg * 8];
#pragma unroll
      for (int fm = 0; fm < 4; ++fm)
#pragma unroll
        for (int fn = 0; fn < 2; ++fn)
          acc[fm][fn] = __builtin_amdgcn_mfma_f32_16x16x32_bf16(af[fm], bg[fn], acc[fm][fn], 0, 0, 0);
    }
#pragma unroll
    for (int fm = 0; fm < 4; ++fm) {
      int o = o0 + wo + fm * 16 + lg * 4;
#pragma unroll
      for (int fn = 0; fn < 2; ++fn) {
        int n = n0 + wn + fn * 16 + lr;
        float4 v;
        v.x = fmaxf(acc[fm][fn][0], 0.f);
        v.y = fmaxf(acc[fm][fn][1], 0.f);
        v.z = fmaxf(acc[fm][fn][2], 0.f);
        v.w = fmaxf(acc[fm][fn][3], 0.f);
        *(float4*)(out + (size_t)bt * 131072 + (size_t)n * 256 + o) = v;
      }
    }
  }
}

extern "C" void kernel_launch(void* const* d_in, const int* in_sizes, int n_in,
                              void* d_out, int out_size, void* d_ws, size_t ws_size,
                              hipStream_t stream) {
  const float* feats = (const float*)d_in[0];
  const float* eig = (const float*)d_in[4];
  const float* param = (const float*)d_in[5];
  float* out = (float*)d_out;

  char* ws = (char*)d_ws;
  ushort* paramT = (ushort*)(ws);                 // 8 MB  [e][o][c]
  ushort* eig_bf = (ushort*)(ws + 8388608);       // 128 KB [e][n]
  ushort* eigT   = (ushort*)(ws + 8519680);       // 128 KB [n][e]
  ushort* x1     = (ushort*)(ws + 8650752);       // 8 MB  [e][bt][c]
  ushort* x3     = (ushort*)(ws + 17039360);      // 16 MB [bt][o][e]

  hipLaunchKernelGGL(k_prep, dim3(512), dim3(256), 0, stream, param, eig, paramT, eig_bf, eigT);
  hipLaunchKernelGGL(k_stage1, dim3(512), dim3(512), 0, stream, feats, eig_bf, x1);
  hipLaunchKernelGGL(k_stage2, dim3(1024), dim3(256), 0, stream, x1, paramT, x3);
  hipLaunchKernelGGL(k_stage3, dim3(512), dim3(512), 0, stream, x3, eigT, out);
}

// Round 13
// 77.321 us; speedup vs baseline: 1.0888x; 1.0888x over previous
//
#include <hip/hip_runtime.h>
#include <hip/hip_bf16.h>
#include <stdint.h>

// BS=16, T=16, N=512, C=128, E=128, OUT=256; P=8192, BT=256
// square[b,t,n,c] = feats[b, n*T+t, c]
// x1[e][bt][c] = sum_n square[n][c]*eig[e][n]          (bf16, ws)
// x3[bt][o][e] = sum_c x1[e][bt][c]*paramT[e][o][c]    (bf16, ws)
// out[bt][n][o] = relu(sum_e x3[bt][o][e]*eigT[n][e])  (f32, d_out)

typedef short bf16x8 __attribute__((ext_vector_type(8)));
typedef float f32x4 __attribute__((ext_vector_type(4)));

__device__ __forceinline__ ushort f2bf(float x) {
  __hip_bfloat16 h = __float2bfloat16(x);   // RNE, lowers to HW cvt on gfx950
  return *(ushort*)&h;
}

// ---------------- prep (merged): paramT + eig_bf + eigT ----------------
__global__ __launch_bounds__(256) void k_prep(const float* __restrict__ param,
                                              const float* __restrict__ eig,
                                              ushort* __restrict__ paramT,
                                              ushort* __restrict__ eig_bf,
                                              ushort* __restrict__ eigT) {
  int bid = blockIdx.x, tid = threadIdx.x;
  if (bid < 256) {
    int o = bid;
    int c = tid & 127, h = tid >> 7;
#pragma unroll 4
    for (int ee = 0; ee < 64; ++ee) {
      int e = h * 64 + ee;
      paramT[(size_t)e * 32768 + o * 128 + c] = f2bf(param[(size_t)o * 16384 + c * 128 + e]);
    }
  } else if (bid < 384) {
    int e = bid - 256;
    eig_bf[e * 512 + tid] = f2bf(eig[e * 512 + tid]);
    eig_bf[e * 512 + 256 + tid] = f2bf(eig[e * 512 + 256 + tid]);
  } else {
    int idx = bid - 384;                 // 0..127, 4 n-rows each
    int n = idx * 4 + (tid >> 6);
    int e0 = (tid & 63) * 2;
    ushort2 pk;
    pk.x = f2bf(eig[(size_t)e0 * 512 + n]);
    pk.y = f2bf(eig[(size_t)(e0 + 1) * 512 + n]);
    *(ushort2*)(eigT + n * 128 + e0) = pk;
  }
}

// ---------------- stage 1: x1[e][bt][c] ----------------
// grid 512 x 512 thr: (bt, c-half) -> 2 independent blocks/CU, 16 waves/CU.
// Role-split staging: threads 0-255 transpose feats (4x4 packed b64 writes),
// threads 256-511 copy eig rows. Cross-block overlap hides HBM latency.
__global__ __launch_bounds__(512) void k_stage1(const float* __restrict__ feats,
                                                const ushort* __restrict__ eig_bf,
                                                ushort* __restrict__ x1) {
  int bid = blockIdx.x;
  int bt = bid >> 1, ch = bid & 1;
  int b = bt >> 4, tt = bt & 15;
  __shared__ ushort As[64 * 72];   // [c-local 64][n-chunk 64, pad 72]
  __shared__ ushort Bs[128 * 72];  // [e 128][n-chunk 64, pad 72]
  int tid = threadIdx.x, l = tid & 63, w = tid >> 6;   // w 0..7
  int wr = (w & 1) * 32;   // c-local offset (2-way)
  int wc = (w >> 1) * 32;  // e offset (4-way)
  int lr = l & 15, lg = l >> 4;
  f32x4 acc[2][2] = {};
  const float* fbase = feats + (size_t)b * (8192 * 128) + (size_t)tt * 128 + ch * 64;

  // staging roles
  int nq = tid & 15;             // A-role: n-quad
  int cq = (tid >> 4) & 15;      // A-role: c-quad (c0 = cq*4, 0..60)
  int lb = tid - 256;            // B-role local id
  int partB = lb & 7, erB = lb >> 3;

  for (int nc = 0; nc < 8; ++nc) {
    int n0 = nc * 64;
    if (tid < 256) {
      // ---- A: transpose 4x4 feats into As[c][n], packed b64 writes ----
      int c0 = cq * 4;
      const float* p = fbase + (size_t)(n0 + nq * 4) * 2048 + c0;
      float4 v0 = *(const float4*)(p);
      float4 v1 = *(const float4*)(p + 2048);
      float4 v2 = *(const float4*)(p + 4096);
      float4 v3 = *(const float4*)(p + 6144);
      const float* a0 = (const float*)&v0;
      const float* a1 = (const float*)&v1;
      const float* a2 = (const float*)&v2;
      const float* a3 = (const float*)&v3;
#pragma unroll
      for (int k = 0; k < 4; ++k) {
        ushort4 q;
        q.x = f2bf(a0[k]);
        q.y = f2bf(a1[k]);
        q.z = f2bf(a2[k]);
        q.w = f2bf(a3[k]);
        *(ushort4*)&As[(c0 + k) * 72 + nq * 4] = q;   // byte 144c+8nq: b64-aligned
      }
    } else {
      // ---- B: eig rows linear copy (128 rows x 128B, 64B/thread) ----
#pragma unroll
      for (int p = 0; p < 4; ++p) {
        int e = erB + p * 32;
        uint4 v = *(const uint4*)(eig_bf + (size_t)e * 512 + n0 + partB * 8);
        *(uint4*)&Bs[e * 72 + partB * 8] = v;
      }
    }
    __syncthreads();
#pragma unroll
    for (int kk = 0; kk < 64; kk += 32) {
      bf16x8 af[2], bg[2];
#pragma unroll
      for (int fm = 0; fm < 2; ++fm)
        af[fm] = *(const bf16x8*)&As[(wr + fm * 16 + lr) * 72 + kk + lg * 8];
#pragma unroll
      for (int fn = 0; fn < 2; ++fn)
        bg[fn] = *(const bf16x8*)&Bs[(wc + fn * 16 + lr) * 72 + kk + lg * 8];
#pragma unroll
      for (int fm = 0; fm < 2; ++fm)
#pragma unroll
        for (int fn = 0; fn < 2; ++fn)
          acc[fm][fn] = __builtin_amdgcn_mfma_f32_16x16x32_bf16(af[fm], bg[fn], acc[fm][fn], 0, 0, 0);
    }
    __syncthreads();
  }
  // epilogue: x1[e][bt][c] 8B packed
#pragma unroll
  for (int fm = 0; fm < 2; ++fm) {
    int c = ch * 64 + wr + fm * 16 + lg * 4;
#pragma unroll
    for (int fn = 0; fn < 2; ++fn) {
      int e = wc + fn * 16 + lr;
      ushort4 pk;
      pk.x = f2bf(acc[fm][fn][0]);
      pk.y = f2bf(acc[fm][fn][1]);
      pk.z = f2bf(acc[fm][fn][2]);
      pk.w = f2bf(acc[fm][fn][3]);
      *(ushort4*)(x1 + (size_t)e * 32768 + bt * 128 + c) = pk;
    }
  }
}

// ---------------- stage 2: x3[bt][o][e] (R11 version) ----------------
// grid 512: (btb 0..3) x (ob 0..3) x (ec 0..31), 4 e per block -> 2 blocks/CU.
__global__ __launch_bounds__(256) void k_stage2(const ushort* __restrict__ x1,
                                                const ushort* __restrict__ paramT,
                                                ushort* __restrict__ x3) {
  int bx = blockIdx.x;
  int btb = bx & 3, ob = (bx >> 2) & 3, ec = bx >> 4;
  int bt0 = btb * 64, o0 = ob * 64, e0 = ec * 4;
  __shared__ ushort As[64 * 136];  // [bt][c pad 136]
  __shared__ ushort Bs[64 * 136];  // [o][c pad 136]
  int tid = threadIdx.x, l = tid & 63, w = tid >> 6;
  int wbt = (w & 1) * 32, wo = (w >> 1) * 32;
  int lr = l & 15, lg = l >> 4;

  float res[2][2][4][4];
#pragma unroll
  for (int ei = 0; ei < 4; ++ei) {
    int e = e0 + ei;
    {
      int part = tid & 15, row = tid >> 4;
#pragma unroll
      for (int p = 0; p < 4; ++p) {
        int r_ = row + p * 16;
        uint4 va = *(const uint4*)(x1 + (size_t)e * 32768 + (bt0 + r_) * 128 + part * 8);
        *(uint4*)&As[r_ * 136 + part * 8] = va;
        uint4 vb = *(const uint4*)(paramT + (size_t)e * 32768 + (o0 + r_) * 128 + part * 8);
        *(uint4*)&Bs[r_ * 136 + part * 8] = vb;
      }
    }
    __syncthreads();
    f32x4 acc[2][2] = {};
#pragma unroll
    for (int kk = 0; kk < 128; kk += 32) {
      bf16x8 af[2], bg[2];
#pragma unroll
      for (int fm = 0; fm < 2; ++fm)
        af[fm] = *(const bf16x8*)&As[(wbt + fm * 16 + lr) * 136 + kk + lg * 8];
#pragma unroll
      for (int fn = 0; fn < 2; ++fn)
        bg[fn] = *(const bf16x8*)&Bs[(wo + fn * 16 + lr) * 136 + kk + lg * 8];
#pragma unroll
      for (int fm = 0; fm < 2; ++fm)
#pragma unroll
        for (int fn = 0; fn < 2; ++fn)
          acc[fm][fn] = __builtin_amdgcn_mfma_f32_16x16x32_bf16(af[fm], bg[fn], acc[fm][fn], 0, 0, 0);
    }
    __syncthreads();
#pragma unroll
    for (int fm = 0; fm < 2; ++fm)
#pragma unroll
      for (int fn = 0; fn < 2; ++fn)
#pragma unroll
        for (int r = 0; r < 4; ++r) res[fm][fn][r][ei] = acc[fm][fn][r];
  }
#pragma unroll
  for (int fm = 0; fm < 2; ++fm) {
    int btl = bt0 + wbt + fm * 16 + lg * 4;
#pragma unroll
    for (int fn = 0; fn < 2; ++fn) {
      int o = o0 + wo + fn * 16 + lr;
#pragma unroll
      for (int r = 0; r < 4; ++r) {
        ushort4 pk;
        pk.x = f2bf(res[fm][fn][r][0]);
        pk.y = f2bf(res[fm][fn][r][1]);
        pk.z = f2bf(res[fm][fn][r][2]);
        pk.w = f2bf(res[fm][fn][r][3]);
        *(ushort4*)(x3 + (size_t)(btl + r) * 32768 + o * 128 + e0) = pk;
      }
    }
  }
}

// ---------------- stage 3: out = relu(x3 @ eigT^T) ----------------
// grid 512 (bt, o-half) x 512 thr: 8 waves (2o x 4n), 16 waves/CU.
// As (x3 o-slice, full e=128) staged once; 4 n-chunks of 128 via Bs.
__global__ __launch_bounds__(512) void k_stage3(const ushort* __restrict__ x3,
                                                const ushort* __restrict__ eigT,
                                                float* __restrict__ out) {
  int bx = blockIdx.x;
  int bt = bx >> 1, ob = bx & 1;
  int o0 = ob * 128;
  __shared__ ushort As[128 * 136];  // [o 128][e 128 pad 136]
  __shared__ ushort Bs[128 * 136];  // [n 128][e 128 pad 136]
  int tid = threadIdx.x, l = tid & 63, w = tid >> 6;   // w 0..7
  int lr = l & 15, lg = l >> 4;
  int wo = (w & 1) * 64;    // o offset (2-way)
  int wn = (w >> 1) * 32;   // n offset (4-way)
  const ushort* pa = x3 + (size_t)bt * 32768 + (size_t)o0 * 128;
  int part = tid & 15, row = tid >> 4;   // 32 rows/pass with 512 thr

  // stage As once: 128 rows x 256B (4 passes)
#pragma unroll
  for (int p = 0; p < 4; ++p) {
    int r_ = row + p * 32;
    uint4 va = *(const uint4*)(pa + (size_t)r_ * 128 + part * 8);
    *(uint4*)&As[r_ * 136 + part * 8] = va;
  }

  for (int nb = 0; nb < 4; ++nb) {
    int n0 = nb * 128;
    __syncthreads();   // As ready (iter0) / prev Bs readers done
#pragma unroll
    for (int p = 0; p < 4; ++p) {
      int r_ = row + p * 32;
      uint4 vb = *(const uint4*)(eigT + (size_t)(n0 + r_) * 128 + part * 8);
      *(uint4*)&Bs[r_ * 136 + part * 8] = vb;
    }
    __syncthreads();
    f32x4 acc[4][2] = {};
#pragma unroll
    for (int kk = 0; kk < 128; kk += 32) {
      bf16x8 af[4], bg[2];
#pragma unroll
      for (int fm = 0; fm < 4; ++fm)
        af[fm] = *(const bf16x8*)&As[(wo + fm * 16 + lr) * 136 + kk + lg * 8];
#pragma unroll
      for (int fn = 0; fn < 2; ++fn)
        bg[fn] = *(const bf16x8*)&Bs[(wn + fn * 16 + lr) * 136 + kk + lg * 8];
#pragma unroll
      for (int fm = 0; fm < 4; ++fm)
#pragma unroll
        for (int fn = 0; fn < 2; ++fn)
          acc[fm][fn] = __builtin_amdgcn_mfma_f32_16x16x32_bf16(af[fm], bg[fn], acc[fm][fn], 0, 0, 0);
    }
#pragma unroll
    for (int fm = 0; fm < 4; ++fm) {
      int o = o0 + wo + fm * 16 + lg * 4;
#pragma unroll
      for (int fn = 0; fn < 2; ++fn) {
        int n = n0 + wn + fn * 16 + lr;
        float4 v;
        v.x = fmaxf(acc[fm][fn][0], 0.f);
        v.y = fmaxf(acc[fm][fn][1], 0.f);
        v.z = fmaxf(acc[fm][fn][2], 0.f);
        v.w = fmaxf(acc[fm][fn][3], 0.f);
        *(float4*)(out + (size_t)bt * 131072 + (size_t)n * 256 + o) = v;
      }
    }
  }
}

extern "C" void kernel_launch(void* const* d_in, const int* in_sizes, int n_in,
                              void* d_out, int out_size, void* d_ws, size_t ws_size,
                              hipStream_t stream) {
  const float* feats = (const float*)d_in[0];
  const float* eig = (const float*)d_in[4];
  const float* param = (const float*)d_in[5];
  float* out = (float*)d_out;

  char* ws = (char*)d_ws;
  ushort* paramT = (ushort*)(ws);                 // 8 MB  [e][o][c]
  ushort* eig_bf = (ushort*)(ws + 8388608);       // 128 KB [e][n]
  ushort* eigT   = (ushort*)(ws + 8519680);       // 128 KB [n][e]
  ushort* x1     = (ushort*)(ws + 8650752);       // 8 MB  [e][bt][c]
  ushort* x3     = (ushort*)(ws + 17039360);      // 16 MB [bt][o][e]

  hipLaunchKernelGGL(k_prep, dim3(512), dim3(256), 0, stream, param, eig, paramT, eig_bf, eigT);
  hipLaunchKernelGGL(k_stage1, dim3(512), dim3(512), 0, stream, feats, eig_bf, x1);
  hipLaunchKernelGGL(k_stage2, dim3(512), dim3(256), 0, stream, x1, paramT, x3);
  hipLaunchKernelGGL(k_stage3, dim3(512), dim3(512), 0, stream, x3, eigT, out);
}

// Round 15
// 76.467 us; speedup vs baseline: 1.1010x; 1.0112x over previous
//
#include <hip/hip_runtime.h>
#include <hip/hip_bf16.h>
#include <stdint.h>

// BS=16, T=16, N=512, C=128, E=128, OUT=256; P=8192, BT=256
// square[b,t,n,c] = feats[b, n*T+t, c]
// x1[e][bt][c] = sum_n square[n][c]*eig[e][n]          (bf16, ws)
// x3[bt][o][e] = sum_c x1[e][bt][c]*paramT[e][o][c]    (bf16, ws)
// out[bt][n][o] = relu(sum_e x3[bt][o][e]*eigT[n][e])  (f32, d_out)

typedef short bf16x8 __attribute__((ext_vector_type(8)));
typedef float f32x4 __attribute__((ext_vector_type(4)));

__device__ __forceinline__ ushort f2bf(float x) {
  __hip_bfloat16 h = __float2bfloat16(x);   // RNE, lowers to HW cvt on gfx950
  return *(ushort*)&h;
}
__device__ __forceinline__ uint pk2bf(float lo, float hi) {
  return (uint)f2bf(lo) | ((uint)f2bf(hi) << 16);
}

// ---------------- fused stage1 + prep ----------------
// grid 832 x 512 thr:
//   bid 0..511 : stage1 for (bt = bid>>1 in 0..255, c-half = bid&1)
//   bid 512..767: paramT[e][o][c] = bf16(param[o][c][e]), o = bid-512
//   bid 768..831: eigT[n][e], 8 n-rows per block (idx = bid-768 in 0..63)
// prep outputs are consumed only by later (stream-serialized) kernels -> race-free;
// prep traffic overlaps stage1's latency-bound execution.
__global__ __launch_bounds__(512) void k_fused1(const float* __restrict__ feats,
                                                const float* __restrict__ eig,
                                                const float* __restrict__ param,
                                                ushort* __restrict__ x1,
                                                ushort* __restrict__ paramT,
                                                ushort* __restrict__ eigT) {
  __shared__ ushort As[64 * 72];   // [c-local 64][n-chunk 64, pad 72]
  __shared__ ushort Bs[128 * 72];  // [e 128][n-chunk 64, pad 72]
  int bid = blockIdx.x, tid = threadIdx.x;

  if (bid >= 512) {
    if (bid < 768) {
      // ---- paramT prep: o = bid-512 (max index: e=127,o=255,c=127 -> 4194303 OK) ----
      int o = bid - 512;
      int c = tid & 127, h = tid >> 7;   // h 0..3
#pragma unroll 4
      for (int ee = 0; ee < 32; ++ee) {
        int e = h * 32 + ee;
        paramT[(size_t)e * 32768 + o * 128 + c] = f2bf(param[(size_t)o * 16384 + c * 128 + e]);
      }
    } else {
      // ---- eigT prep: idx 0..63, n = idx*8 + (tid>>6) <= 511 OK ----
      int idx = bid - 768;
      int n = idx * 8 + (tid >> 6);
      int e0 = (tid & 63) * 2;
      ushort2 pk;
      pk.x = f2bf(eig[(size_t)e0 * 512 + n]);
      pk.y = f2bf(eig[(size_t)(e0 + 1) * 512 + n]);
      *(ushort2*)(eigT + n * 128 + e0) = pk;
    }
    return;
  }

  // ---- stage1: bt = bid>>1 in 0..255 (max feats idx 16777215, max x1 idx 4194303) ----
  int bt = bid >> 1, ch = bid & 1;
  int b = bt >> 4, tt = bt & 15;
  int l = tid & 63, w = tid >> 6;   // w 0..7
  int wr = (w & 1) * 32;   // c-local offset (2-way)
  int wc = (w >> 1) * 32;  // e offset (4-way)
  int lr = l & 15, lg = l >> 4;
  f32x4 acc[2][2] = {};
  const float* fbase = feats + (size_t)b * (8192 * 128) + (size_t)tt * 128 + ch * 64;

  // staging roles
  int nq = tid & 15;             // A-role: n-quad
  int cq = (tid >> 4) & 15;      // A-role: c-quad (c0 = cq*4, 0..60)
  int lb = tid - 256;            // B-role local id
  int partB = lb & 7, erB = lb >> 3;   // 8 parts x 8 floats; 32 rows/pass

  for (int nc = 0; nc < 8; ++nc) {
    int n0 = nc * 64;
    if (tid < 256) {
      // ---- A: transpose 4x4 feats into As[c][n], packed b64 writes ----
      int c0 = cq * 4;
      const float* p = fbase + (size_t)(n0 + nq * 4) * 2048 + c0;
      float4 v0 = *(const float4*)(p);
      float4 v1 = *(const float4*)(p + 2048);
      float4 v2 = *(const float4*)(p + 4096);
      float4 v3 = *(const float4*)(p + 6144);
      const float* a0 = (const float*)&v0;
      const float* a1 = (const float*)&v1;
      const float* a2 = (const float*)&v2;
      const float* a3 = (const float*)&v3;
#pragma unroll
      for (int k = 0; k < 4; ++k) {
        ushort4 q;
        q.x = f2bf(a0[k]);
        q.y = f2bf(a1[k]);
        q.z = f2bf(a2[k]);
        q.w = f2bf(a3[k]);
        *(ushort4*)&As[(c0 + k) * 72 + nq * 4] = q;   // byte 144c+8nq: b64-aligned
      }
    } else {
      // ---- B: eig rows from f32, convert + packed b128 writes ----
#pragma unroll
      for (int p = 0; p < 4; ++p) {
        int e = erB + p * 32;
        const float* src = eig + (size_t)e * 512 + n0 + partB * 8;
        float4 u0 = *(const float4*)(src);
        float4 u1 = *(const float4*)(src + 4);
        uint4 pk;
        pk.x = pk2bf(u0.x, u0.y);
        pk.y = pk2bf(u0.z, u0.w);
        pk.z = pk2bf(u1.x, u1.y);
        pk.w = pk2bf(u1.z, u1.w);
        *(uint4*)&Bs[e * 72 + partB * 8] = pk;   // byte 144e+16partB: 16B-aligned
      }
    }
    __syncthreads();
#pragma unroll
    for (int kk = 0; kk < 64; kk += 32) {
      bf16x8 af[2], bg[2];
#pragma unroll
      for (int fm = 0; fm < 2; ++fm)
        af[fm] = *(const bf16x8*)&As[(wr + fm * 16 + lr) * 72 + kk + lg * 8];
#pragma unroll
      for (int fn = 0; fn < 2; ++fn)
        bg[fn] = *(const bf16x8*)&Bs[(wc + fn * 16 + lr) * 72 + kk + lg * 8];
#pragma unroll
      for (int fm = 0; fm < 2; ++fm)
#pragma unroll
        for (int fn = 0; fn < 2; ++fn)
          acc[fm][fn] = __builtin_amdgcn_mfma_f32_16x16x32_bf16(af[fm], bg[fn], acc[fm][fn], 0, 0, 0);
    }
    __syncthreads();
  }
  // epilogue: x1[e][bt][c] 8B packed
#pragma unroll
  for (int fm = 0; fm < 2; ++fm) {
    int c = ch * 64 + wr + fm * 16 + lg * 4;
#pragma unroll
    for (int fn = 0; fn < 2; ++fn) {
      int e = wc + fn * 16 + lr;
      ushort4 pk;
      pk.x = f2bf(acc[fm][fn][0]);
      pk.y = f2bf(acc[fm][fn][1]);
      pk.z = f2bf(acc[fm][fn][2]);
      pk.w = f2bf(acc[fm][fn][3]);
      *(ushort4*)(x1 + (size_t)e * 32768 + bt * 128 + c) = pk;
    }
  }
}

// ---------------- stage 2: x3[bt][o][e] ----------------
// grid 512: (btb 0..3) x (ob 0..3) x (ec 0..31), 4 e per block -> 2 blocks/CU.
__global__ __launch_bounds__(256) void k_stage2(const ushort* __restrict__ x1,
                                                const ushort* __restrict__ paramT,
                                                ushort* __restrict__ x3) {
  int bx = blockIdx.x;
  int btb = bx & 3, ob = (bx >> 2) & 3, ec = bx >> 4;
  int bt0 = btb * 64, o0 = ob * 64, e0 = ec * 4;
  __shared__ ushort As[64 * 136];  // [bt][c pad 136]
  __shared__ ushort Bs[64 * 136];  // [o][c pad 136]
  int tid = threadIdx.x, l = tid & 63, w = tid >> 6;
  int wbt = (w & 1) * 32, wo = (w >> 1) * 32;
  int lr = l & 15, lg = l >> 4;

  float res[2][2][4][4];
#pragma unroll
  for (int ei = 0; ei < 4; ++ei) {
    int e = e0 + ei;
    {
      int part = tid & 15, row = tid >> 4;
#pragma unroll
      for (int p = 0; p < 4; ++p) {
        int r_ = row + p * 16;
        uint4 va = *(const uint4*)(x1 + (size_t)e * 32768 + (bt0 + r_) * 128 + part * 8);
        *(uint4*)&As[r_ * 136 + part * 8] = va;
        uint4 vb = *(const uint4*)(paramT + (size_t)e * 32768 + (o0 + r_) * 128 + part * 8);
        *(uint4*)&Bs[r_ * 136 + part * 8] = vb;
      }
    }
    __syncthreads();
    f32x4 acc[2][2] = {};
#pragma unroll
    for (int kk = 0; kk < 128; kk += 32) {
      bf16x8 af[2], bg[2];
#pragma unroll
      for (int fm = 0; fm < 2; ++fm)
        af[fm] = *(const bf16x8*)&As[(wbt + fm * 16 + lr) * 136 + kk + lg * 8];
#pragma unroll
      for (int fn = 0; fn < 2; ++fn)
        bg[fn] = *(const bf16x8*)&Bs[(wo + fn * 16 + lr) * 136 + kk + lg * 8];
#pragma unroll
      for (int fm = 0; fm < 2; ++fm)
#pragma unroll
        for (int fn = 0; fn < 2; ++fn)
          acc[fm][fn] = __builtin_amdgcn_mfma_f32_16x16x32_bf16(af[fm], bg[fn], acc[fm][fn], 0, 0, 0);
    }
    __syncthreads();
#pragma unroll
    for (int fm = 0; fm < 2; ++fm)
#pragma unroll
      for (int fn = 0; fn < 2; ++fn)
#pragma unroll
        for (int r = 0; r < 4; ++r) res[fm][fn][r][ei] = acc[fm][fn][r];
  }
#pragma unroll
  for (int fm = 0; fm < 2; ++fm) {
    int btl = bt0 + wbt + fm * 16 + lg * 4;
#pragma unroll
    for (int fn = 0; fn < 2; ++fn) {
      int o = o0 + wo + fn * 16 + lr;
#pragma unroll
      for (int r = 0; r < 4; ++r) {
        ushort4 pk;
        pk.x = f2bf(res[fm][fn][r][0]);
        pk.y = f2bf(res[fm][fn][r][1]);
        pk.z = f2bf(res[fm][fn][r][2]);
        pk.w = f2bf(res[fm][fn][r][3]);
        *(ushort4*)(x3 + (size_t)(btl + r) * 32768 + o * 128 + e0) = pk;
      }
    }
  }
}

// ---------------- stage 3: out = relu(x3 @ eigT^T) ----------------
// grid 512 (bt, o-half) x 512 thr: 8 waves (2o x 4n), 16 waves/CU.
// As (x3 o-slice, full e=128) staged once; 4 n-chunks of 128 via Bs.
__global__ __launch_bounds__(512) void k_stage3(const ushort* __restrict__ x3,
                                                const ushort* __restrict__ eigT,
                                                float* __restrict__ out) {
  int bx = blockIdx.x;
  int bt = bx >> 1, ob = bx & 1;
  int o0 = ob * 128;
  __shared__ ushort As[128 * 136];  // [o 128][e 128 pad 136]
  __shared__ ushort Bs[128 * 136];  // [n 128][e 128 pad 136]
  int tid = threadIdx.x, l = tid & 63, w = tid >> 6;   // w 0..7
  int lr = l & 15, lg = l >> 4;
  int wo = (w & 1) * 64;    // o offset (2-way)
  int wn = (w >> 1) * 32;   // n offset (4-way)
  const ushort* pa = x3 + (size_t)bt * 32768 + (size_t)o0 * 128;
  int part = tid & 15, row = tid >> 4;   // 32 rows/pass with 512 thr

  // stage As once: 128 rows x 256B (4 passes)
#pragma unroll
  for (int p = 0; p < 4; ++p) {
    int r_ = row + p * 32;
    uint4 va = *(const uint4*)(pa + (size_t)r_ * 128 + part * 8);
    *(uint4*)&As[r_ * 136 + part * 8] = va;
  }

  for (int nb = 0; nb < 4; ++nb) {
    int n0 = nb * 128;
    __syncthreads();   // As ready (iter0) / prev Bs readers done
#pragma unroll
    for (int p = 0; p < 4; ++p) {
      int r_ = row + p * 32;
      uint4 vb = *(const uint4*)(eigT + (size_t)(n0 + r_) * 128 + part * 8);
      *(uint4*)&Bs[r_ * 136 + part * 8] = vb;
    }
    __syncthreads();
    f32x4 acc[4][2] = {};
#pragma unroll
    for (int kk = 0; kk < 128; kk += 32) {
      bf16x8 af[4], bg[2];
#pragma unroll
      for (int fm = 0; fm < 4; ++fm)
        af[fm] = *(const bf16x8*)&As[(wo + fm * 16 + lr) * 136 + kk + lg * 8];
#pragma unroll
      for (int fn = 0; fn < 2; ++fn)
        bg[fn] = *(const bf16x8*)&Bs[(wn + fn * 16 + lr) * 136 + kk + lg * 8];
#pragma unroll
      for (int fm = 0; fm < 4; ++fm)
#pragma unroll
        for (int fn = 0; fn < 2; ++fn)
          acc[fm][fn] = __builtin_amdgcn_mfma_f32_16x16x32_bf16(af[fm], bg[fn], acc[fm][fn], 0, 0, 0);
    }
#pragma unroll
    for (int fm = 0; fm < 4; ++fm) {
      int o = o0 + wo + fm * 16 + lg * 4;
#pragma unroll
      for (int fn = 0; fn < 2; ++fn) {
        int n = n0 + wn + fn * 16 + lr;
        float4 v;
        v.x = fmaxf(acc[fm][fn][0], 0.f);
        v.y = fmaxf(acc[fm][fn][1], 0.f);
        v.z = fmaxf(acc[fm][fn][2], 0.f);
        v.w = fmaxf(acc[fm][fn][3], 0.f);
        *(float4*)(out + (size_t)bt * 131072 + (size_t)n * 256 + o) = v;
      }
    }
  }
}

extern "C" void kernel_launch(void* const* d_in, const int* in_sizes, int n_in,
                              void* d_out, int out_size, void* d_ws, size_t ws_size,
                              hipStream_t stream) {
  const float* feats = (const float*)d_in[0];
  const float* eig = (const float*)d_in[4];
  const float* param = (const float*)d_in[5];
  float* out = (float*)d_out;

  char* ws = (char*)d_ws;
  ushort* paramT = (ushort*)(ws);                 // 8 MB  [e][o][c]
  ushort* eigT   = (ushort*)(ws + 8519680);       // 128 KB [n][e]
  ushort* x1     = (ushort*)(ws + 8650752);       // 8 MB  [e][bt][c]
  ushort* x3     = (ushort*)(ws + 17039360);      // 16 MB [bt][o][e]

  hipLaunchKernelGGL(k_fused1, dim3(832), dim3(512), 0, stream, feats, eig, param, x1, paramT, eigT);
  hipLaunchKernelGGL(k_stage2, dim3(512), dim3(256), 0, stream, x1, paramT, x3);
  hipLaunchKernelGGL(k_stage3, dim3(512), dim3(512), 0, stream, x3, eigT, out);
}

// Round 16
// 76.372 us; speedup vs baseline: 1.1023x; 1.0012x over previous
//
#include <hip/hip_runtime.h>
#include <hip/hip_bf16.h>
#include <stdint.h>

// BS=16, T=16, N=512, C=128, E=128, OUT=256; P=8192, BT=256
// square[b,t,n,c] = feats[b, n*T+t, c]
// x1[e][bt][c] = sum_n square[n][c]*eig[e][n]          (bf16, ws)
// x3[bt][o][e] = sum_c x1[e][bt][c]*paramT[e][o][c]    (bf16, ws)
// out[bt][n][o] = relu(sum_e x3[bt][o][e]*eigT[n][e])  (f32, d_out)

typedef short bf16x8 __attribute__((ext_vector_type(8)));
typedef float f32x4 __attribute__((ext_vector_type(4)));

__device__ __forceinline__ ushort f2bf(float x) {
  __hip_bfloat16 h = __float2bfloat16(x);   // RNE, lowers to HW cvt on gfx950
  return *(ushort*)&h;
}
__device__ __forceinline__ uint pk2bf(float lo, float hi) {
  return (uint)f2bf(lo) | ((uint)f2bf(hi) << 16);
}

// ---------------- fused stage1 + prep ----------------
// grid 832 x 512 thr:
//   bid 0..511 : stage1 for (bt = bid>>1 in 0..255, c-half = bid&1)
//   bid 512..767: paramT[e][o][c] = bf16(param[o][c][e]), o = bid-512
//   bid 768..831: eigT[n][e], 8 n-rows per block (idx = bid-768 in 0..63)
__global__ __launch_bounds__(512) void k_fused1(const float* __restrict__ feats,
                                                const float* __restrict__ eig,
                                                const float* __restrict__ param,
                                                ushort* __restrict__ x1,
                                                ushort* __restrict__ paramT,
                                                ushort* __restrict__ eigT) {
  __shared__ ushort As[64 * 72];   // [c-local 64][n-chunk 64, pad 72]
  __shared__ ushort Bs[128 * 72];  // [e 128][n-chunk 64, pad 72]
  int bid = blockIdx.x, tid = threadIdx.x;

  if (bid >= 512) {
    if (bid < 768) {
      int o = bid - 512;
      int c = tid & 127, h = tid >> 7;   // h 0..3
#pragma unroll 4
      for (int ee = 0; ee < 32; ++ee) {
        int e = h * 32 + ee;
        paramT[(size_t)e * 32768 + o * 128 + c] = f2bf(param[(size_t)o * 16384 + c * 128 + e]);
      }
    } else {
      int idx = bid - 768;
      int n = idx * 8 + (tid >> 6);
      int e0 = (tid & 63) * 2;
      ushort2 pk;
      pk.x = f2bf(eig[(size_t)e0 * 512 + n]);
      pk.y = f2bf(eig[(size_t)(e0 + 1) * 512 + n]);
      *(ushort2*)(eigT + n * 128 + e0) = pk;
    }
    return;
  }

  // ---- stage1 ----
  int bt = bid >> 1, ch = bid & 1;
  int b = bt >> 4, tt = bt & 15;
  int l = tid & 63, w = tid >> 6;   // w 0..7
  int wr = (w & 1) * 32;   // c-local offset (2-way)
  int wc = (w >> 1) * 32;  // e offset (4-way)
  int lr = l & 15, lg = l >> 4;
  f32x4 acc[2][2] = {};
  const float* fbase = feats + (size_t)b * (8192 * 128) + (size_t)tt * 128 + ch * 64;

  int nq = tid & 15;             // A-role: n-quad
  int cq = (tid >> 4) & 15;      // A-role: c-quad
  int lb = tid - 256;            // B-role local id
  int partB = lb & 7, erB = lb >> 3;

  for (int nc = 0; nc < 8; ++nc) {
    int n0 = nc * 64;
    if (tid < 256) {
      int c0 = cq * 4;
      const float* p = fbase + (size_t)(n0 + nq * 4) * 2048 + c0;
      float4 v0 = *(const float4*)(p);
      float4 v1 = *(const float4*)(p + 2048);
      float4 v2 = *(const float4*)(p + 4096);
      float4 v3 = *(const float4*)(p + 6144);
      const float* a0 = (const float*)&v0;
      const float* a1 = (const float*)&v1;
      const float* a2 = (const float*)&v2;
      const float* a3 = (const float*)&v3;
#pragma unroll
      for (int k = 0; k < 4; ++k) {
        ushort4 q;
        q.x = f2bf(a0[k]);
        q.y = f2bf(a1[k]);
        q.z = f2bf(a2[k]);
        q.w = f2bf(a3[k]);
        *(ushort4*)&As[(c0 + k) * 72 + nq * 4] = q;
      }
    } else {
#pragma unroll
      for (int p = 0; p < 4; ++p) {
        int e = erB + p * 32;
        const float* src = eig + (size_t)e * 512 + n0 + partB * 8;
        float4 u0 = *(const float4*)(src);
        float4 u1 = *(const float4*)(src + 4);
        uint4 pk;
        pk.x = pk2bf(u0.x, u0.y);
        pk.y = pk2bf(u0.z, u0.w);
        pk.z = pk2bf(u1.x, u1.y);
        pk.w = pk2bf(u1.z, u1.w);
        *(uint4*)&Bs[e * 72 + partB * 8] = pk;
      }
    }
    __syncthreads();
#pragma unroll
    for (int kk = 0; kk < 64; kk += 32) {
      bf16x8 af[2], bg[2];
#pragma unroll
      for (int fm = 0; fm < 2; ++fm)
        af[fm] = *(const bf16x8*)&As[(wr + fm * 16 + lr) * 72 + kk + lg * 8];
#pragma unroll
      for (int fn = 0; fn < 2; ++fn)
        bg[fn] = *(const bf16x8*)&Bs[(wc + fn * 16 + lr) * 72 + kk + lg * 8];
#pragma unroll
      for (int fm = 0; fm < 2; ++fm)
#pragma unroll
        for (int fn = 0; fn < 2; ++fn)
          acc[fm][fn] = __builtin_amdgcn_mfma_f32_16x16x32_bf16(af[fm], bg[fn], acc[fm][fn], 0, 0, 0);
    }
    __syncthreads();
  }
#pragma unroll
  for (int fm = 0; fm < 2; ++fm) {
    int c = ch * 64 + wr + fm * 16 + lg * 4;
#pragma unroll
    for (int fn = 0; fn < 2; ++fn) {
      int e = wc + fn * 16 + lr;
      ushort4 pk;
      pk.x = f2bf(acc[fm][fn][0]);
      pk.y = f2bf(acc[fm][fn][1]);
      pk.z = f2bf(acc[fm][fn][2]);
      pk.w = f2bf(acc[fm][fn][3]);
      *(ushort4*)(x1 + (size_t)e * 32768 + bt * 128 + c) = pk;
    }
  }
}

// ---------------- stage 2: x3[bt][o][e] ----------------
// grid 512 x 512 thr: (btb 0..3) x (ob 0..3) x (ec 0..31), 4 e per block.
// 8 waves tile 64bt x 64o as 2x4 (32x16 each) -> 16 waves/CU; stores stay ushort4.
__global__ __launch_bounds__(512) void k_stage2(const ushort* __restrict__ x1,
                                                const ushort* __restrict__ paramT,
                                                ushort* __restrict__ x3) {
  int bx = blockIdx.x;
  int btb = bx & 3, ob = (bx >> 2) & 3, ec = bx >> 4;
  int bt0 = btb * 64, o0 = ob * 64, e0 = ec * 4;
  __shared__ ushort As[64 * 136];  // [bt][c pad 136]
  __shared__ ushort Bs[64 * 136];  // [o][c pad 136]
  int tid = threadIdx.x, l = tid & 63, w = tid >> 6;   // w 0..7
  int wbt = (w & 1) * 32;   // bt offset (2-way)
  int wo = (w >> 1) * 16;   // o offset (4-way)
  int lr = l & 15, lg = l >> 4;

  float res[2][4][4];   // [fm][reg][ei]
#pragma unroll
  for (int ei = 0; ei < 4; ++ei) {
    int e = e0 + ei;
    {
      int part = tid & 15, row = tid >> 4;   // 32 rows/pass, 2 passes
#pragma unroll
      for (int p = 0; p < 2; ++p) {
        int r_ = row + p * 32;
        uint4 va = *(const uint4*)(x1 + (size_t)e * 32768 + (bt0 + r_) * 128 + part * 8);
        *(uint4*)&As[r_ * 136 + part * 8] = va;
        uint4 vb = *(const uint4*)(paramT + (size_t)e * 32768 + (o0 + r_) * 128 + part * 8);
        *(uint4*)&Bs[r_ * 136 + part * 8] = vb;
      }
    }
    __syncthreads();
    f32x4 acc[2] = {};
#pragma unroll
    for (int kk = 0; kk < 128; kk += 32) {
      bf16x8 af[2], bg;
#pragma unroll
      for (int fm = 0; fm < 2; ++fm)
        af[fm] = *(const bf16x8*)&As[(wbt + fm * 16 + lr) * 136 + kk + lg * 8];
      bg = *(const bf16x8*)&Bs[(wo + lr) * 136 + kk + lg * 8];
#pragma unroll
      for (int fm = 0; fm < 2; ++fm)
        acc[fm] = __builtin_amdgcn_mfma_f32_16x16x32_bf16(af[fm], bg, acc[fm], 0, 0, 0);
    }
    __syncthreads();
#pragma unroll
    for (int fm = 0; fm < 2; ++fm)
#pragma unroll
      for (int r = 0; r < 4; ++r) res[fm][r][ei] = acc[fm][r];
  }
#pragma unroll
  for (int fm = 0; fm < 2; ++fm) {
    int btl = bt0 + wbt + fm * 16 + lg * 4;
    int o = o0 + wo + lr;
#pragma unroll
    for (int r = 0; r < 4; ++r) {
      ushort4 pk;
      pk.x = f2bf(res[fm][r][0]);
      pk.y = f2bf(res[fm][r][1]);
      pk.z = f2bf(res[fm][r][2]);
      pk.w = f2bf(res[fm][r][3]);
      *(ushort4*)(x3 + (size_t)(btl + r) * 32768 + o * 128 + e0) = pk;
    }
  }
}

// ---------------- stage 3: out = relu(x3 @ eigT^T) ----------------
// grid 512 (bt, o-half) x 512 thr: 8 waves (2o x 4n), 16 waves/CU.
__global__ __launch_bounds__(512) void k_stage3(const ushort* __restrict__ x3,
                                                const ushort* __restrict__ eigT,
                                                float* __restrict__ out) {
  int bx = blockIdx.x;
  int bt = bx >> 1, ob = bx & 1;
  int o0 = ob * 128;
  __shared__ ushort As[128 * 136];  // [o 128][e 128 pad 136]
  __shared__ ushort Bs[128 * 136];  // [n 128][e 128 pad 136]
  int tid = threadIdx.x, l = tid & 63, w = tid >> 6;   // w 0..7
  int lr = l & 15, lg = l >> 4;
  int wo = (w & 1) * 64;    // o offset (2-way)
  int wn = (w >> 1) * 32;   // n offset (4-way)
  const ushort* pa = x3 + (size_t)bt * 32768 + (size_t)o0 * 128;
  int part = tid & 15, row = tid >> 4;   // 32 rows/pass

  // stage As once: 128 rows x 256B (4 passes)
#pragma unroll
  for (int p = 0; p < 4; ++p) {
    int r_ = row + p * 32;
    uint4 va = *(const uint4*)(pa + (size_t)r_ * 128 + part * 8);
    *(uint4*)&As[r_ * 136 + part * 8] = va;
  }

  for (int nb = 0; nb < 4; ++nb) {
    int n0 = nb * 128;
    __syncthreads();
#pragma unroll
    for (int p = 0; p < 4; ++p) {
      int r_ = row + p * 32;
      uint4 vb = *(const uint4*)(eigT + (size_t)(n0 + r_) * 128 + part * 8);
      *(uint4*)&Bs[r_ * 136 + part * 8] = vb;
    }
    __syncthreads();
    f32x4 acc[4][2] = {};
#pragma unroll
    for (int kk = 0; kk < 128; kk += 32) {
      bf16x8 af[4], bg[2];
#pragma unroll
      for (int fm = 0; fm < 4; ++fm)
        af[fm] = *(const bf16x8*)&As[(wo + fm * 16 + lr) * 136 + kk + lg * 8];
#pragma unroll
      for (int fn = 0; fn < 2; ++fn)
        bg[fn] = *(const bf16x8*)&Bs[(wn + fn * 16 + lr) * 136 + kk + lg * 8];
#pragma unroll
      for (int fm = 0; fm < 4; ++fm)
#pragma unroll
        for (int fn = 0; fn < 2; ++fn)
          acc[fm][fn] = __builtin_amdgcn_mfma_f32_16x16x32_bf16(af[fm], bg[fn], acc[fm][fn], 0, 0, 0);
    }
#pragma unroll
    for (int fm = 0; fm < 4; ++fm) {
      int o = o0 + wo + fm * 16 + lg * 4;
#pragma unroll
      for (int fn = 0; fn < 2; ++fn) {
        int n = n0 + wn + fn * 16 + lr;
        float4 v;
        v.x = fmaxf(acc[fm][fn][0], 0.f);
        v.y = fmaxf(acc[fm][fn][1], 0.f);
        v.z = fmaxf(acc[fm][fn][2], 0.f);
        v.w = fmaxf(acc[fm][fn][3], 0.f);
        *(float4*)(out + (size_t)bt * 131072 + (size_t)n * 256 + o) = v;
      }
    }
  }
}

extern "C" void kernel_launch(void* const* d_in, const int* in_sizes, int n_in,
                              void* d_out, int out_size, void* d_ws, size_t ws_size,
                              hipStream_t stream) {
  const float* feats = (const float*)d_in[0];
  const float* eig = (const float*)d_in[4];
  const float* param = (const float*)d_in[5];
  float* out = (float*)d_out;

  char* ws = (char*)d_ws;
  ushort* paramT = (ushort*)(ws);                 // 8 MB  [e][o][c]
  ushort* eigT   = (ushort*)(ws + 8519680);       // 128 KB [n][e]
  ushort* x1     = (ushort*)(ws + 8650752);       // 8 MB  [e][bt][c]
  ushort* x3     = (ushort*)(ws + 17039360);      // 16 MB [bt][o][e]

  hipLaunchKernelGGL(k_fused1, dim3(832), dim3(512), 0, stream, feats, eig, param, x1, paramT, eigT);
  hipLaunchKernelGGL(k_stage2, dim3(512), dim3(512), 0, stream, x1, paramT, x3);
  hipLaunchKernelGGL(k_stage3, dim3(512), dim3(512), 0, stream, x3, eigT, out);
}